// Round 11
// baseline (5660.799 us; speedup 1.0000x reference)
//
#include <hip/hip_runtime.h>

#define T_STEPS 64
#define BATCH   128
#define HID     1024
#define VOCAB   10000
#define VPAD    10240
#define NSPLIT  8
#define KCHUNK  256

typedef unsigned short ushort_t;
typedef __attribute__((ext_vector_type(8))) short bf16x8_t;
typedef __attribute__((ext_vector_type(4))) float f32x4_t;

typedef const unsigned int __attribute__((address_space(1)))* gptr1_t;
typedef unsigned int __attribute__((address_space(3)))* lptr3_t;

#if defined(__has_builtin)
#if __has_builtin(__builtin_amdgcn_global_load_lds)
#define HAVE_GLL 1
#endif
#endif

__device__ inline unsigned short f2bf(float f) {
    unsigned int u = __float_as_uint(f);
    u += 0x7fffu + ((u >> 16) & 1u);
    return (unsigned short)(u >> 16);
}

// ---------------------------------------------------------------------------
__global__ void init_h(const float* __restrict__ hidden,
                       float* __restrict__ h0, float* __restrict__ h1)
{
    int i = blockIdx.x * blockDim.x + threadIdx.x;
    if (i < BATCH * HID) {
        h0[i] = hidden[i];
        h1[i] = hidden[BATCH * HID + i];
    }
}

__global__ void final_h(const float* __restrict__ h0, const float* __restrict__ h1,
                        float* __restrict__ out)
{
    int i = blockIdx.x * blockDim.x + threadIdx.x;
    if (i < BATCH * HID) {
        out[i] = h0[i];
        out[BATCH * HID + i] = h1[i];
    }
}

__global__ __launch_bounds__(256)
void gather_kernel(const int* __restrict__ ids, const float* __restrict__ emb,
                   float* __restrict__ xemb)
{
    const int row = blockIdx.x;
    const int c4 = threadIdx.x * 4;
    float4 v = *(const float4*)&emb[(size_t)ids[row] * HID + c4];
    *(float4*)&xemb[(size_t)row * HID + c4] = v;
}

__global__ __launch_bounds__(256)
void woutT_kernel(const float* __restrict__ Wout, ushort_t* __restrict__ WT)
{
    __shared__ float ld[32][33];
    const int v0 = blockIdx.x * 32, k0 = blockIdx.y * 32;
    const int r = threadIdx.x >> 3;
    const int c4 = (threadIdx.x & 7) * 4;
    #pragma unroll
    for (int q = 0; q < 4; ++q) {
        int v = v0 + c4 + q;
        float val = 0.0f;
        if (v < VOCAB) val = Wout[(size_t)(k0 + r) * VOCAB + v];
        ld[c4 + q][r] = val;
    }
    __syncthreads();
    ushort4 o;
    o.x = f2bf(ld[r][c4 + 0]);
    o.y = f2bf(ld[r][c4 + 1]);
    o.z = f2bf(ld[r][c4 + 2]);
    o.w = f2bf(ld[r][c4 + 3]);
    *(ushort4*)&WT[(size_t)(v0 + r) * HID + k0 + c4] = o;
}

// ---------------------------------------------------------------------------
// agemm_k: rz partial GEMM. 512 threads, TM=128, TN=64, TK=32, 8 tiles,
// DOUBLE-BUFFERED global_load_lds with counted vmcnt (never 0 mid-loop).
// grid (32, 8, 2). Per-output FMA order: k ascending (canary preserved).
// ---------------------------------------------------------------------------
__global__ __launch_bounds__(512)
void agemm_k(const float* __restrict__ xemb_t0,
             const float* __restrict__ h0, const float* __restrict__ h1,
             const float* __restrict__ Wr, const float* __restrict__ Wz,
             float* __restrict__ part_rz, int do0, int do1)
{
    const int layer = blockIdx.z;
    if (layer == 0 && !do0) return;
    if (layer == 1 && !do1) return;

    __shared__ float As[2][128 * 32];   // 16 KB each
    __shared__ float Bs[2][32 * 64];    // 8 KB each
    const int tid = threadIdx.x;
    const int w = tid >> 6;
    const int lane = tid & 63;
    const int tx = tid & 15;            // col group (4 cols)
    const int ty = tid >> 4;            // row base 0..31
    const int j0 = blockIdx.x * 64;
    const int kbase = blockIdx.y * KCHUNK;

    const float* W = ((j0 < HID) ? Wr : Wz) + (size_t)layer * (2 * HID * HID);
    const int jc = j0 & (HID - 1);
    const float* A_lo = layer ? h0 : xemb_t0;
    const float* A_hi = layer ? h1 : h0;

    // per-thread staging coords (A: 2 issues; B: 1 issue -> 3 gll/tile)
    const int ar0 = (w * 2) * 8 + (lane >> 3);        // issue 0 row
    const int ar1 = (w * 2 + 1) * 8 + (lane >> 3);    // issue 1 row
    const int ac0 = ((lane & 7) ^ (ar0 & 3)) * 4;     // swizzled src chunk
    const int ac1 = ((lane & 7) ^ (ar1 & 3)) * 4;
    const int bkr = w * 4 + (lane >> 4);              // 0..31
    const int bcc = (lane & 15) * 4;

    float acc[4][4] = {};

#define A_STAGE(buf, t)                                                        \
    {                                                                          \
        const int kg0 = kbase + (t) * 32;                                      \
        const float* src = (kg0 < HID) ? A_lo : A_hi;                          \
        const int kmod = kg0 & (HID - 1);                                      \
        const float* ga0 = src + (size_t)ar0 * HID + kmod + ac0;               \
        const float* ga1 = src + (size_t)ar1 * HID + kmod + ac1;               \
        const float* gb  = W + (size_t)(kg0 + bkr) * HID + jc + bcc;           \
        __builtin_amdgcn_global_load_lds((gptr1_t)(const void*)ga0,            \
            (lptr3_t)(void*)(&As[buf][(w * 2) * 256]), 16, 0, 0);              \
        __builtin_amdgcn_global_load_lds((gptr1_t)(const void*)ga1,            \
            (lptr3_t)(void*)(&As[buf][(w * 2 + 1) * 256]), 16, 0, 0);          \
        __builtin_amdgcn_global_load_lds((gptr1_t)(const void*)gb,             \
            (lptr3_t)(void*)(&Bs[buf][w * 256]), 16, 0, 0);                    \
    }

#ifdef HAVE_GLL
    A_STAGE(0, 0)
    A_STAGE(1, 1)
    #pragma unroll
    for (int t = 0; t < 8; ++t) {
        if (t < 7) { asm volatile("s_waitcnt vmcnt(3)" ::: "memory"); }
        else       { asm volatile("s_waitcnt vmcnt(0)" ::: "memory"); }
        __builtin_amdgcn_s_barrier();
        __builtin_amdgcn_sched_barrier(0);
        const int buf = t & 1;
        #pragma unroll
        for (int kk = 0; kk < 32; kk += 4) {
            f32x4_t b[4];
            #pragma unroll
            for (int q = 0; q < 4; ++q)
                b[q] = *(const f32x4_t*)&Bs[buf][(kk + q) * 64 + tx * 4];
            #pragma unroll
            for (int i = 0; i < 4; ++i) {
                int row = ty + i * 32;
                int cswz = (((kk >> 2) ^ (row & 3)) << 2);
                f32x4_t a = *(const f32x4_t*)&As[buf][row * 32 + cswz];
                #pragma unroll
                for (int q = 0; q < 4; ++q) {
                    acc[i][0] += a[q] * b[q][0];
                    acc[i][1] += a[q] * b[q][1];
                    acc[i][2] += a[q] * b[q][2];
                    acc[i][3] += a[q] * b[q][3];
                }
            }
        }
        __builtin_amdgcn_sched_barrier(0);
        __builtin_amdgcn_s_barrier();
        __builtin_amdgcn_sched_barrier(0);
        if (t + 2 < 8) A_STAGE(buf, t + 2)
    }
#else
    for (int t = 0; t < 8; ++t) {
        const int kg0 = kbase + t * 32;
        const float* src = (kg0 < HID) ? A_lo : A_hi;
        const int kmod = kg0 & (HID - 1);
        *(float4*)&As[0][(w * 2) * 256 + lane * 4] =
            *(const float4*)(src + (size_t)ar0 * HID + kmod + ac0);
        *(float4*)&As[0][(w * 2 + 1) * 256 + lane * 4] =
            *(const float4*)(src + (size_t)ar1 * HID + kmod + ac1);
        *(float4*)&Bs[0][w * 256 + lane * 4] =
            *(const float4*)(W + (size_t)(kg0 + bkr) * HID + jc + bcc);
        __syncthreads();
        #pragma unroll
        for (int kk = 0; kk < 32; kk += 4) {
            f32x4_t b[4];
            #pragma unroll
            for (int q = 0; q < 4; ++q)
                b[q] = *(const f32x4_t*)&Bs[0][(kk + q) * 64 + tx * 4];
            #pragma unroll
            for (int i = 0; i < 4; ++i) {
                int row = ty + i * 32;
                int cswz = (((kk >> 2) ^ (row & 3)) << 2);
                f32x4_t a = *(const f32x4_t*)&As[0][row * 32 + cswz];
                #pragma unroll
                for (int q = 0; q < 4; ++q) {
                    acc[i][0] += a[q] * b[q][0];
                    acc[i][1] += a[q] * b[q][1];
                    acc[i][2] += a[q] * b[q][2];
                    acc[i][3] += a[q] * b[q][3];
                }
            }
        }
        __syncthreads();
    }
#endif
#undef A_STAGE

    float* dst = part_rz + (size_t)(layer * NSPLIT + blockIdx.y) * (BATCH * 2 * HID);
    #pragma unroll
    for (int i = 0; i < 4; ++i) {
        int row = ty + i * 32;
        float4 v;
        v.x = acc[i][0]; v.y = acc[i][1]; v.z = acc[i][2]; v.w = acc[i][3];
        *(float4*)&dst[(size_t)row * 2048 + j0 + tx * 4] = v;
    }
}

// ---------------------------------------------------------------------------
// aact: r = tanh(sum_splits part_rz[.., j<H] + br);  rh = r * h_old
// ---------------------------------------------------------------------------
__global__ __launch_bounds__(256)
void aact_kernel(const float* __restrict__ part_rz,
                 const float* __restrict__ br,
                 const float* __restrict__ h0, const float* __restrict__ h1,
                 float* __restrict__ rh0, float* __restrict__ rh1,
                 int do0, int do1)
{
    const int layer = blockIdx.y;
    if (layer == 0 && !do0) return;
    if (layer == 1 && !do1) return;
    const int idx4 = (blockIdx.x * 256 + threadIdx.x) * 4;
    const int b = idx4 >> 10, j = idx4 & (HID - 1);
    const float* p = part_rz + (size_t)layer * NSPLIT * (BATCH * 2 * HID)
                   + (size_t)b * 2048 + j;
    float4 s = {0.f, 0.f, 0.f, 0.f};
    #pragma unroll
    for (int sp = 0; sp < NSPLIT; ++sp) {
        float4 v = *(const float4*)&p[(size_t)sp * (BATCH * 2 * HID)];
        s.x += v.x; s.y += v.y; s.z += v.z; s.w += v.w;
    }
    float4 bb = *(const float4*)&br[layer * HID + j];
    float4 hv = *(const float4*)&(layer ? h1 : h0)[idx4];
    float4 rh;
    rh.x = tanhf(s.x + bb.x) * hv.x;
    rh.y = tanhf(s.y + bb.y) * hv.y;
    rh.z = tanhf(s.z + bb.z) * hv.z;
    rh.w = tanhf(s.w + bb.w) * hv.w;
    *(float4*)&(layer ? rh1 : rh0)[idx4] = rh;
}

// ---------------------------------------------------------------------------
// bgemm_k: g partial GEMM. 512 threads, TM=128, TN=32, TK=64, 4 tiles,
// DOUBLE-BUFFERED, counted vmcnt. grid (32, 8, 2).
// ---------------------------------------------------------------------------
__global__ __launch_bounds__(512)
void bgemm_k(const float* __restrict__ xemb_t0,
             const float* __restrict__ h0, const float* __restrict__ h1,
             const float* __restrict__ rh0, const float* __restrict__ rh1,
             const float* __restrict__ Wg,
             float* __restrict__ part_g, int do0, int do1)
{
    const int layer = blockIdx.z;
    if (layer == 0 && !do0) return;
    if (layer == 1 && !do1) return;

    __shared__ float As[2][128 * 64];   // 32 KB each
    __shared__ float Bs[2][64 * 32];    // 8 KB each
    const int tid = threadIdx.x;
    const int w = tid >> 6;
    const int lane = tid & 63;
    const int tx = tid & 15;            // col group (2 cols)
    const int ty = tid >> 4;            // 0..31
    const int j0 = blockIdx.x * 32;
    const int kbase = blockIdx.y * KCHUNK;

    const float* W = Wg + (size_t)layer * (2 * HID * HID);
    const float* A_lo = layer ? h0 : xemb_t0;
    const float* A_hi = layer ? rh1 : rh0;

    // A: 4 issues (rows ia*4 + lane>>4, 16-chunk swizzle); B: 1 issue
    int arr[4], acc_c[4];
    #pragma unroll
    for (int ii = 0; ii < 4; ++ii) {
        arr[ii] = (w * 4 + ii) * 4 + (lane >> 4);     // 0..127
        acc_c[ii] = ((lane & 15) ^ (arr[ii] & 3)) * 4;
    }
    const int bkr = w * 8 + (lane >> 3);              // 0..63
    const int bcc = (lane & 7) * 4;

    float acc[4][2] = {};

#define B_STAGE(buf, t)                                                        \
    {                                                                          \
        const int kg0 = kbase + (t) * 64;                                      \
        const float* src = (kg0 < HID) ? A_lo : A_hi;                          \
        const int kmod = kg0 & (HID - 1);                                      \
        _Pragma("unroll")                                                      \
        for (int ii = 0; ii < 4; ++ii) {                                       \
            const float* ga = src + (size_t)arr[ii] * HID + kmod + acc_c[ii];  \
            __builtin_amdgcn_global_load_lds((gptr1_t)(const void*)ga,         \
                (lptr3_t)(void*)(&As[buf][(w * 4 + ii) * 256]), 16, 0, 0);     \
        }                                                                      \
        const float* gb = W + (size_t)(kg0 + bkr) * HID + j0 + bcc;            \
        __builtin_amdgcn_global_load_lds((gptr1_t)(const void*)gb,             \
            (lptr3_t)(void*)(&Bs[buf][w * 256]), 16, 0, 0);                    \
    }

#ifdef HAVE_GLL
    B_STAGE(0, 0)
    B_STAGE(1, 1)
    #pragma unroll
    for (int t = 0; t < 4; ++t) {
        if (t < 3) { asm volatile("s_waitcnt vmcnt(5)" ::: "memory"); }
        else       { asm volatile("s_waitcnt vmcnt(0)" ::: "memory"); }
        __builtin_amdgcn_s_barrier();
        __builtin_amdgcn_sched_barrier(0);
        const int buf = t & 1;
        #pragma unroll
        for (int kk = 0; kk < 64; kk += 4) {
            float2 b[4];
            #pragma unroll
            for (int q = 0; q < 4; ++q)
                b[q] = *(const float2*)&Bs[buf][(kk + q) * 32 + tx * 2];
            #pragma unroll
            for (int i = 0; i < 4; ++i) {
                int row = ty + i * 32;
                int cswz = (((kk >> 2) ^ (row & 3)) << 2);
                f32x4_t a = *(const f32x4_t*)&As[buf][row * 64 + cswz];
                #pragma unroll
                for (int q = 0; q < 4; ++q) {
                    acc[i][0] += a[q] * b[q].x;
                    acc[i][1] += a[q] * b[q].y;
                }
            }
        }
        __builtin_amdgcn_sched_barrier(0);
        __builtin_amdgcn_s_barrier();
        __builtin_amdgcn_sched_barrier(0);
        if (t + 2 < 4) B_STAGE(buf, t + 2)
    }
#else
    for (int t = 0; t < 4; ++t) {
        const int kg0 = kbase + t * 64;
        const float* src = (kg0 < HID) ? A_lo : A_hi;
        const int kmod = kg0 & (HID - 1);
        #pragma unroll
        for (int ii = 0; ii < 4; ++ii)
            *(float4*)&As[0][(w * 4 + ii) * 256 + lane * 4] =
                *(const float4*)(src + (size_t)arr[ii] * HID + kmod + acc_c[ii]);
        *(float4*)&Bs[0][w * 256 + lane * 4] =
            *(const float4*)(W + (size_t)(kg0 + bkr) * HID + j0 + bcc);
        __syncthreads();
        #pragma unroll
        for (int kk = 0; kk < 64; kk += 4) {
            float2 b[4];
            #pragma unroll
            for (int q = 0; q < 4; ++q)
                b[q] = *(const float2*)&Bs[0][(kk + q) * 32 + tx * 2];
            #pragma unroll
            for (int i = 0; i < 4; ++i) {
                int row = ty + i * 32;
                int cswz = (((kk >> 2) ^ (row & 3)) << 2);
                f32x4_t a = *(const f32x4_t*)&As[0][row * 64 + cswz];
                #pragma unroll
                for (int q = 0; q < 4; ++q) {
                    acc[i][0] += a[q] * b[q].x;
                    acc[i][1] += a[q] * b[q].y;
                }
            }
        }
        __syncthreads();
    }
#endif
#undef B_STAGE

    float* dst = part_g + (size_t)(layer * NSPLIT + blockIdx.y) * (BATCH * HID);
    #pragma unroll
    for (int i = 0; i < 4; ++i) {
        int row = ty + i * 32;
        float2 v;
        v.x = acc[i][0]; v.y = acc[i][1];
        *(float2*)&dst[(size_t)row * HID + j0 + tx * 2] = v;
    }
}

// ---------------------------------------------------------------------------
// bact: z/g reduction + tanh + h update (unchanged numerics)
// ---------------------------------------------------------------------------
__global__ __launch_bounds__(256)
void bact_kernel(const float* __restrict__ part_rz, const float* __restrict__ part_g,
                 const float* __restrict__ bz, const float* __restrict__ bg,
                 float* __restrict__ h0, float* __restrict__ h1,
                 ushort_t* __restrict__ h1bf, int t1, int do0, int do1)
{
    const int layer = blockIdx.y;
    if (layer == 0 && !do0) return;
    if (layer == 1 && !do1) return;
    const int idx4 = (blockIdx.x * 256 + threadIdx.x) * 4;
    const int b = idx4 >> 10, j = idx4 & (HID - 1);

    const float* pz = part_rz + (size_t)layer * NSPLIT * (BATCH * 2 * HID)
                    + (size_t)b * 2048 + HID + j;
    float4 sz = {0.f, 0.f, 0.f, 0.f};
    #pragma unroll
    for (int sp = 0; sp < NSPLIT; ++sp) {
        float4 v = *(const float4*)&pz[(size_t)sp * (BATCH * 2 * HID)];
        sz.x += v.x; sz.y += v.y; sz.z += v.z; sz.w += v.w;
    }
    float4 bzv = *(const float4*)&bz[layer * HID + j];
    float4 z;
    z.x = tanhf(sz.x + bzv.x); z.y = tanhf(sz.y + bzv.y);
    z.z = tanhf(sz.z + bzv.z); z.w = tanhf(sz.w + bzv.w);

    const float* pg = part_g + (size_t)layer * NSPLIT * (BATCH * HID) + idx4;
    float4 sg = {0.f, 0.f, 0.f, 0.f};
    #pragma unroll
    for (int sp = 0; sp < NSPLIT; ++sp) {
        float4 v = *(const float4*)&pg[(size_t)sp * (BATCH * HID)];
        sg.x += v.x; sg.y += v.y; sg.z += v.z; sg.w += v.w;
    }
    float4 bgv = *(const float4*)&bg[layer * HID + j];
    float4 g;
    g.x = tanhf(sg.x + bgv.x); g.y = tanhf(sg.y + bgv.y);
    g.z = tanhf(sg.z + bgv.z); g.w = tanhf(sg.w + bgv.w);

    float* h = layer ? h1 : h0;
    float4 hv = *(const float4*)&h[idx4];
    float4 hn;
    hn.x = (1.0f - z.x) * hv.x + z.x * g.x;
    hn.y = (1.0f - z.y) * hv.y + z.y * g.y;
    hn.z = (1.0f - z.z) * hv.z + z.z * g.z;
    hn.w = (1.0f - z.w) * hv.w + z.w * g.w;
    *(float4*)&h[idx4] = hn;

    if (layer == 1) {
        ushort4 o;
        o.x = f2bf(hn.x); o.y = f2bf(hn.y); o.z = f2bf(hn.z); o.w = f2bf(hn.w);
        *(ushort4*)&h1bf[(size_t)t1 * (BATCH * HID) + idx4] = o;
    }
}

// ---------------------------------------------------------------------------
// Logits MFMA GEMM (+ XCD-aware block swizzle; body unchanged)
// ---------------------------------------------------------------------------
__global__ __launch_bounds__(256)
void logits_mfma_kernel(const ushort_t* __restrict__ Abf,
                        const ushort_t* __restrict__ BT,
                        const float* __restrict__ bout,
                        float* __restrict__ out)
{
    __shared__ ushort_t As[128 * 64];
    __shared__ ushort_t Bs[128 * 64];
    const int tid = threadIdx.x;
    const int wave = tid >> 6, lane = tid & 63;

    // bijective XCD swizzle: 5120 blocks, 640 per XCD
    const int wg = blockIdx.y * gridDim.x + blockIdx.x;
    const int swz = (wg & 7) * 640 + (wg >> 3);
    const int m0 = (swz / 80) * 128, n0 = (swz % 80) * 128;
    const int wr = wave >> 1, wc = wave & 1;

    const int srow = lane >> 3;
    const int sch = (lane & 7) ^ (srow & 7);
    const int lrow = lane & 15, lhi = lane >> 4;

    f32x4_t acc[4][4] = {};

    for (int k0 = 0; k0 < HID; k0 += 64) {
        #pragma unroll
        for (int i = 0; i < 4; ++i) {
            int issue = wave * 4 + i;
            int row = issue * 8 + srow;
            const ushort_t* ga = Abf + (size_t)(m0 + row) * HID + k0 + sch * 8;
            const ushort_t* gb = BT + (size_t)(n0 + row) * HID + k0 + sch * 8;
#ifdef HAVE_GLL
            __builtin_amdgcn_global_load_lds((gptr1_t)(const void*)ga,
                                             (lptr3_t)(void*)(As + issue * 512), 16, 0, 0);
            __builtin_amdgcn_global_load_lds((gptr1_t)(const void*)gb,
                                             (lptr3_t)(void*)(Bs + issue * 512), 16, 0, 0);
#else
            *(bf16x8_t*)(As + issue * 512 + lane * 8) = *(const bf16x8_t*)ga;
            *(bf16x8_t*)(Bs + issue * 512 + lane * 8) = *(const bf16x8_t*)gb;
#endif
        }
        __syncthreads();

        bf16x8_t af[4][2], bfm[4][2];
        const char* Ab = (const char*)As;
        const char* Bb = (const char*)Bs;
        #pragma unroll
        for (int m = 0; m < 4; ++m) {
            int row = wr * 64 + m * 16 + lrow;
            #pragma unroll
            for (int ks = 0; ks < 2; ++ks) {
                int off = row * 128 + (((ks * 4 + lhi) ^ (lrow & 7)) * 16);
                af[m][ks] = *(const bf16x8_t*)(Ab + off);
            }
        }
        #pragma unroll
        for (int n = 0; n < 4; ++n) {
            int row = wc * 64 + n * 16 + lrow;
            #pragma unroll
            for (int ks = 0; ks < 2; ++ks) {
                int off = row * 128 + (((ks * 4 + lhi) ^ (lrow & 7)) * 16);
                bfm[n][ks] = *(const bf16x8_t*)(Bb + off);
            }
        }
        #pragma unroll
        for (int m = 0; m < 4; ++m)
            #pragma unroll
            for (int n = 0; n < 4; ++n)
                #pragma unroll
                for (int ks = 0; ks < 2; ++ks)
                    acc[m][n] = __builtin_amdgcn_mfma_f32_16x16x32_bf16(
                        af[m][ks], bfm[n][ks], acc[m][n], 0, 0, 0);
        __syncthreads();
    }

    #pragma unroll
    for (int m = 0; m < 4; ++m) {
        int row = m0 + wr * 64 + m * 16 + lhi * 4;
        #pragma unroll
        for (int n = 0; n < 4; ++n) {
            int col = n0 + wc * 64 + n * 16 + lrow;
            if (col < VOCAB) {
                float bo = bout[col];
                #pragma unroll
                for (int q = 0; q < 4; ++q)
                    out[(size_t)(row + q) * VOCAB + col] = tanhf(acc[m][n][q] + bo);
            }
        }
    }
}

// ---------------------------------------------------------------------------
extern "C" void kernel_launch(void* const* d_in, const int* in_sizes, int n_in,
                              void* d_out, int out_size, void* d_ws, size_t ws_size,
                              hipStream_t stream)
{
    const int*   inputs = (const int*)  d_in[0];
    const float* hidden = (const float*)d_in[1];
    const float* emb    = (const float*)d_in[2];
    const float* Wr     = (const float*)d_in[3];
    const float* br     = (const float*)d_in[4];
    const float* Wz     = (const float*)d_in[5];
    const float* bz     = (const float*)d_in[6];
    const float* Wg     = (const float*)d_in[7];
    const float* bg     = (const float*)d_in[8];
    const float* Wout   = (const float*)d_in[9];
    const float* bout   = (const float*)d_in[10];
    float* out = (float*)d_out;

    const size_t BH = BATCH * HID;                 // 131072

    float* ws = (float*)d_ws;
    float* h0      = ws;                           // BH
    float* h1      = h0 + BH;                      // BH
    float* rh0     = h1 + BH;                      // BH
    float* rh1     = rh0 + BH;                     // BH
    float* part_rz = rh1 + BH;                     // 2*8*262144
    float* part_g  = part_rz + 2 * NSPLIT * (BATCH * 2 * HID);  // 2*8*131072
    float* xemb    = part_g + 2 * NSPLIT * (BATCH * HID);       // T*B*H
    ushort_t* h1bf = (ushort_t*)(xemb + (size_t)T_STEPS * BH);  // T*B*H bf16
    ushort_t* WT   = h1bf + (size_t)T_STEPS * BH;               // VPAD*H bf16

    init_h<<<(int)(BH + 255) / 256, 256, 0, stream>>>(hidden, h0, h1);
    gather_kernel<<<T_STEPS * BATCH, 256, 0, stream>>>(inputs, emb, xemb);
    woutT_kernel<<<dim3(VPAD / 32, HID / 32), 256, 0, stream>>>(Wout, WT);

    for (int s = 0; s <= T_STEPS; ++s) {
        int do0 = (s < T_STEPS) ? 1 : 0;
        int do1 = (s >= 1) ? 1 : 0;
        const float* xemb_t0 = xemb + (size_t)s * BH;
        agemm_k<<<dim3(32, NSPLIT, 2), 512, 0, stream>>>(
            xemb_t0, h0, h1, Wr, Wz, part_rz, do0, do1);
        aact_kernel<<<dim3(128, 2), 256, 0, stream>>>(
            part_rz, br, h0, h1, rh0, rh1, do0, do1);
        bgemm_k<<<dim3(32, NSPLIT, 2), 512, 0, stream>>>(
            xemb_t0, h0, h1, rh0, rh1, Wg, part_g, do0, do1);
        bact_kernel<<<dim3(128, 2), 256, 0, stream>>>(
            part_rz, part_g, bz, bg, h0, h1, h1bf, s - 1, do0, do1);
    }

    final_h<<<(int)(BH + 255) / 256, 256, 0, stream>>>(
        h0, h1, out + (size_t)T_STEPS * BATCH * VOCAB);

    logits_mfma_kernel<<<dim3(VPAD / 128, 8192 / 128), 256, 0, stream>>>(
        h1bf, WT, bout, out);
}

// Round 13
// 4067.150 us; speedup vs baseline: 1.3918x; 1.3918x over previous
//
#include <hip/hip_runtime.h>

#define T_STEPS 64
#define BATCH   128
#define HID     1024
#define VOCAB   10000
#define VPAD    10240
#define NSPLIT  8
#define KCHUNK  256

typedef unsigned short ushort_t;
typedef __attribute__((ext_vector_type(8))) short bf16x8_t;
typedef __attribute__((ext_vector_type(4))) float f32x4_t;

typedef const unsigned int __attribute__((address_space(1)))* gptr1_t;
typedef unsigned int __attribute__((address_space(3)))* lptr3_t;

#if defined(__has_builtin)
#if __has_builtin(__builtin_amdgcn_global_load_lds)
#define HAVE_GLL 1
#endif
#endif

__device__ inline unsigned short f2bf(float f) {
    unsigned int u = __float_as_uint(f);
    u += 0x7fffu + ((u >> 16) & 1u);
    return (unsigned short)(u >> 16);
}

// ---------------------------------------------------------------------------
__global__ void init_h(const float* __restrict__ hidden,
                       float* __restrict__ h0, float* __restrict__ h1)
{
    int i = blockIdx.x * blockDim.x + threadIdx.x;
    if (i < BATCH * HID) {
        h0[i] = hidden[i];
        h1[i] = hidden[BATCH * HID + i];
    }
}

__global__ void final_h(const float* __restrict__ h0, const float* __restrict__ h1,
                        float* __restrict__ out)
{
    int i = blockIdx.x * blockDim.x + threadIdx.x;
    if (i < BATCH * HID) {
        out[i] = h0[i];
        out[BATCH * HID + i] = h1[i];
    }
}

__global__ __launch_bounds__(256)
void gather_kernel(const int* __restrict__ ids, const float* __restrict__ emb,
                   float* __restrict__ xemb)
{
    const int row = blockIdx.x;
    const int c4 = threadIdx.x * 4;
    float4 v = *(const float4*)&emb[(size_t)ids[row] * HID + c4];
    *(float4*)&xemb[(size_t)row * HID + c4] = v;
}

__global__ __launch_bounds__(256)
void woutT_kernel(const float* __restrict__ Wout, ushort_t* __restrict__ WT)
{
    __shared__ float ld[32][33];
    const int v0 = blockIdx.x * 32, k0 = blockIdx.y * 32;
    const int r = threadIdx.x >> 3;
    const int c4 = (threadIdx.x & 7) * 4;
    #pragma unroll
    for (int q = 0; q < 4; ++q) {
        int v = v0 + c4 + q;
        float val = 0.0f;
        if (v < VOCAB) val = Wout[(size_t)(k0 + r) * VOCAB + v];
        ld[c4 + q][r] = val;
    }
    __syncthreads();
    ushort4 o;
    o.x = f2bf(ld[r][c4 + 0]);
    o.y = f2bf(ld[r][c4 + 1]);
    o.z = f2bf(ld[r][c4 + 2]);
    o.w = f2bf(ld[r][c4 + 3]);
    *(ushort4*)&WT[(size_t)(v0 + r) * HID + k0 + c4] = o;
}

// ---------------------------------------------------------------------------
// agemm_k: rz partial GEMM. 256 threads (4 waves), TM=128, TN=64, TK=64,
// 8x4 per-thread tile (0.75 B/FLOP vs R10's 1.0). grid (32, 8, 2).
// Staging identical to R10 (global_load_lds 16B, source chunk-swizzle).
// Per-output FMA order: tiles asc, kk asc, q asc -> canary 1.1063840e13.
// ---------------------------------------------------------------------------
__global__ __launch_bounds__(256)
void agemm_k(const float* __restrict__ xemb_t0,
             const float* __restrict__ h0, const float* __restrict__ h1,
             const float* __restrict__ Wr, const float* __restrict__ Wz,
             float* __restrict__ part_rz, int do0, int do1)
{
    const int layer = blockIdx.z;
    if (layer == 0 && !do0) return;
    if (layer == 1 && !do1) return;

    __shared__ float As[128 * 64];   // 32 KB
    __shared__ float Bs[64 * 64];    // 16 KB
    const int tid = threadIdx.x;
    const int w = tid >> 6;          // 0..3
    const int lane = tid & 63;
    const int lrow = lane >> 4;      // 0..3
    const int lchunk = lane & 15;    // 0..15
    const int tx = tid & 15;         // col group (4 cols)
    const int ty = tid >> 4;         // row base 0..15
    const int j0 = blockIdx.x * 64;
    const int kbase = blockIdx.y * KCHUNK;

    const float* W = ((j0 < HID) ? Wr : Wz) + (size_t)layer * (2 * HID * HID);
    const int jc = j0 & (HID - 1);
    const float* A_lo = layer ? h0 : xemb_t0;
    const float* A_hi = layer ? h1 : h0;

    float acc[8][4] = {};

    for (int kt0 = 0; kt0 < KCHUNK; kt0 += 64) {
        const int kg0 = kbase + kt0;
        const float* src = (kg0 < HID) ? A_lo : A_hi;
        const int kmod = kg0 & (HID - 1);
        if (kt0 > 0) __syncthreads();
        // stage A: 32 issues, 8 per wave
        #pragma unroll
        for (int ii = 0; ii < 8; ++ii) {
            int issue = w * 8 + ii;                  // 0..31
            int r = issue * 4 + lrow;                // 0..127
            int gc = (lchunk ^ (r & 3)) * 4;
            const float* ga = src + (size_t)r * HID + kmod + gc;
#ifdef HAVE_GLL
            __builtin_amdgcn_global_load_lds((gptr1_t)(const void*)ga,
                (lptr3_t)(void*)(As + issue * 256), 16, 0, 0);
#else
            *(float4*)&As[issue * 256 + lane * 4] = *(const float4*)ga;
#endif
        }
        // stage B: 16 issues, 4 per wave
        #pragma unroll
        for (int ii = 0; ii < 4; ++ii) {
            int issue = w * 4 + ii;                  // 0..15
            int kr = issue * 4 + lrow;               // 0..63
            const float* gb = W + (size_t)(kg0 + kr) * HID + jc + lchunk * 4;
#ifdef HAVE_GLL
            __builtin_amdgcn_global_load_lds((gptr1_t)(const void*)gb,
                (lptr3_t)(void*)(Bs + issue * 256), 16, 0, 0);
#else
            *(float4*)&Bs[issue * 256 + lane * 4] = *(const float4*)gb;
#endif
        }
        __syncthreads();
        // compute: per thread 8 rows (ty+16i) x 4 cols (tx*4)
        #pragma unroll
        for (int kk = 0; kk < 64; kk += 4) {
            f32x4_t b[4];
            #pragma unroll
            for (int q = 0; q < 4; ++q)
                b[q] = *(const f32x4_t*)&Bs[(kk + q) * 64 + tx * 4];
            #pragma unroll
            for (int i = 0; i < 8; ++i) {
                int row = ty + i * 16;
                int cswz = (((kk >> 2) ^ (row & 3)) << 2);
                f32x4_t a = *(const f32x4_t*)&As[row * 64 + cswz];
                #pragma unroll
                for (int q = 0; q < 4; ++q) {
                    acc[i][0] += a[q] * b[q][0];
                    acc[i][1] += a[q] * b[q][1];
                    acc[i][2] += a[q] * b[q][2];
                    acc[i][3] += a[q] * b[q][3];
                }
            }
        }
    }

    float* dst = part_rz + (size_t)(layer * NSPLIT + blockIdx.y) * (BATCH * 2 * HID);
    #pragma unroll
    for (int i = 0; i < 8; ++i) {
        int row = ty + i * 16;
        float4 v;
        v.x = acc[i][0]; v.y = acc[i][1]; v.z = acc[i][2]; v.w = acc[i][3];
        *(float4*)&dst[(size_t)row * 2048 + j0 + tx * 4] = v;
    }
}

// ---------------------------------------------------------------------------
// aact: r = tanh(sum_splits part_rz[.., j<H] + br);  rh = r * h_old
// (R10 verbatim)
// ---------------------------------------------------------------------------
__global__ __launch_bounds__(256)
void aact_kernel(const float* __restrict__ part_rz,
                 const float* __restrict__ br,
                 const float* __restrict__ h0, const float* __restrict__ h1,
                 float* __restrict__ rh0, float* __restrict__ rh1,
                 int do0, int do1)
{
    const int layer = blockIdx.y;
    if (layer == 0 && !do0) return;
    if (layer == 1 && !do1) return;
    const int idx4 = (blockIdx.x * 256 + threadIdx.x) * 4;
    const int b = idx4 >> 10, j = idx4 & (HID - 1);
    const float* p = part_rz + (size_t)layer * NSPLIT * (BATCH * 2 * HID)
                   + (size_t)b * 2048 + j;
    float4 s = {0.f, 0.f, 0.f, 0.f};
    #pragma unroll
    for (int sp = 0; sp < NSPLIT; ++sp) {
        float4 v = *(const float4*)&p[(size_t)sp * (BATCH * 2 * HID)];
        s.x += v.x; s.y += v.y; s.z += v.z; s.w += v.w;
    }
    float4 bb = *(const float4*)&br[layer * HID + j];
    float4 hv = *(const float4*)&(layer ? h1 : h0)[idx4];
    float4 rh;
    rh.x = tanhf(s.x + bb.x) * hv.x;
    rh.y = tanhf(s.y + bb.y) * hv.y;
    rh.z = tanhf(s.z + bb.z) * hv.z;
    rh.w = tanhf(s.w + bb.w) * hv.w;
    *(float4*)&(layer ? rh1 : rh0)[idx4] = rh;
}

// ---------------------------------------------------------------------------
// bgemm_k: g partial GEMM. 256 threads, TM=128, TN=32, TK=64,
// 4x4 per-thread tile (1.0 B/FLOP vs R10's 1.5). grid (32, 8, 2).
//   A2 (layer0) = k<H ? xemb : rh0 ; (layer1) = k<H ? h0 : rh1 (pure DMA)
// ---------------------------------------------------------------------------
__global__ __launch_bounds__(256)
void bgemm_k(const float* __restrict__ xemb_t0,
             const float* __restrict__ h0, const float* __restrict__ h1,
             const float* __restrict__ rh0, const float* __restrict__ rh1,
             const float* __restrict__ Wg,
             float* __restrict__ part_g, int do0, int do1)
{
    const int layer = blockIdx.z;
    if (layer == 0 && !do0) return;
    if (layer == 1 && !do1) return;

    __shared__ float As[128 * 64];   // 32 KB
    __shared__ float Bs[64 * 32];    // 8 KB
    const int tid = threadIdx.x;
    const int w = tid >> 6;
    const int lane = tid & 63;
    const int lrow = lane >> 4;
    const int lchunk = lane & 15;
    const int tx = tid & 7;          // col group (4 cols)
    const int ty = tid >> 3;         // 0..31
    const int j0 = blockIdx.x * 32;
    const int kbase = blockIdx.y * KCHUNK;

    const float* W = Wg + (size_t)layer * (2 * HID * HID);
    const float* A_lo = layer ? h0 : xemb_t0;
    const float* A_hi = layer ? rh1 : rh0;

    float acc[4][4] = {};

    for (int kt0 = 0; kt0 < KCHUNK; kt0 += 64) {
        const int kg0 = kbase + kt0;
        const float* src = (kg0 < HID) ? A_lo : A_hi;
        const int kmod = kg0 & (HID - 1);
        if (kt0 > 0) __syncthreads();
        // stage A: 32 issues, 8 per wave (same layout as agemm)
        #pragma unroll
        for (int ii = 0; ii < 8; ++ii) {
            int issue = w * 8 + ii;
            int r = issue * 4 + lrow;
            int gc = (lchunk ^ (r & 3)) * 4;
            const float* ga = src + (size_t)r * HID + kmod + gc;
#ifdef HAVE_GLL
            __builtin_amdgcn_global_load_lds((gptr1_t)(const void*)ga,
                (lptr3_t)(void*)(As + issue * 256), 16, 0, 0);
#else
            *(float4*)&As[issue * 256 + lane * 4] = *(const float4*)ga;
#endif
        }
        // stage B: 8 issues, 2 per wave; issue covers 8 k-rows x 32 cols
        #pragma unroll
        for (int ii = 0; ii < 2; ++ii) {
            int issue = w * 2 + ii;                  // 0..7
            int kr = issue * 8 + (lane >> 3);        // 0..63
            const float* gb = W + (size_t)(kg0 + kr) * HID + j0 + (lane & 7) * 4;
#ifdef HAVE_GLL
            __builtin_amdgcn_global_load_lds((gptr1_t)(const void*)gb,
                (lptr3_t)(void*)(Bs + issue * 256), 16, 0, 0);
#else
            *(float4*)&Bs[issue * 256 + lane * 4] = *(const float4*)gb;
#endif
        }
        __syncthreads();
        // compute: per thread 4 rows (ty+32i) x 4 cols (tx*4)
        #pragma unroll
        for (int kk = 0; kk < 64; kk += 4) {
            f32x4_t b[4];
            #pragma unroll
            for (int q = 0; q < 4; ++q)
                b[q] = *(const f32x4_t*)&Bs[(kk + q) * 32 + tx * 4];
            #pragma unroll
            for (int i = 0; i < 4; ++i) {
                int row = ty + i * 32;
                int cswz = (((kk >> 2) ^ (row & 3)) << 2);
                f32x4_t a = *(const f32x4_t*)&As[row * 64 + cswz];
                #pragma unroll
                for (int q = 0; q < 4; ++q) {
                    acc[i][0] += a[q] * b[q][0];
                    acc[i][1] += a[q] * b[q][1];
                    acc[i][2] += a[q] * b[q][2];
                    acc[i][3] += a[q] * b[q][3];
                }
            }
        }
    }

    float* dst = part_g + (size_t)(layer * NSPLIT + blockIdx.y) * (BATCH * HID);
    #pragma unroll
    for (int i = 0; i < 4; ++i) {
        int row = ty + i * 32;
        float4 v;
        v.x = acc[i][0]; v.y = acc[i][1]; v.z = acc[i][2]; v.w = acc[i][3];
        *(float4*)&dst[(size_t)row * HID + j0 + tx * 4] = v;
    }
}

// ---------------------------------------------------------------------------
// bact: z/g reduction + tanh + h update (R10 verbatim)
// ---------------------------------------------------------------------------
__global__ __launch_bounds__(256)
void bact_kernel(const float* __restrict__ part_rz, const float* __restrict__ part_g,
                 const float* __restrict__ bz, const float* __restrict__ bg,
                 float* __restrict__ h0, float* __restrict__ h1,
                 ushort_t* __restrict__ h1bf, int t1, int do0, int do1)
{
    const int layer = blockIdx.y;
    if (layer == 0 && !do0) return;
    if (layer == 1 && !do1) return;
    const int idx4 = (blockIdx.x * 256 + threadIdx.x) * 4;
    const int b = idx4 >> 10, j = idx4 & (HID - 1);

    const float* pz = part_rz + (size_t)layer * NSPLIT * (BATCH * 2 * HID)
                    + (size_t)b * 2048 + HID + j;
    float4 sz = {0.f, 0.f, 0.f, 0.f};
    #pragma unroll
    for (int sp = 0; sp < NSPLIT; ++sp) {
        float4 v = *(const float4*)&pz[(size_t)sp * (BATCH * 2 * HID)];
        sz.x += v.x; sz.y += v.y; sz.z += v.z; sz.w += v.w;
    }
    float4 bzv = *(const float4*)&bz[layer * HID + j];
    float4 z;
    z.x = tanhf(sz.x + bzv.x); z.y = tanhf(sz.y + bzv.y);
    z.z = tanhf(sz.z + bzv.z); z.w = tanhf(sz.w + bzv.w);

    const float* pg = part_g + (size_t)layer * NSPLIT * (BATCH * HID) + idx4;
    float4 sg = {0.f, 0.f, 0.f, 0.f};
    #pragma unroll
    for (int sp = 0; sp < NSPLIT; ++sp) {
        float4 v = *(const float4*)&pg[(size_t)sp * (BATCH * HID)];
        sg.x += v.x; sg.y += v.y; sg.z += v.z; sg.w += v.w;
    }
    float4 bgv = *(const float4*)&bg[layer * HID + j];
    float4 g;
    g.x = tanhf(sg.x + bgv.x); g.y = tanhf(sg.y + bgv.y);
    g.z = tanhf(sg.z + bgv.z); g.w = tanhf(sg.w + bgv.w);

    float* h = layer ? h1 : h0;
    float4 hv = *(const float4*)&h[idx4];
    float4 hn;
    hn.x = (1.0f - z.x) * hv.x + z.x * g.x;
    hn.y = (1.0f - z.y) * hv.y + z.y * g.y;
    hn.z = (1.0f - z.z) * hv.z + z.z * g.z;
    hn.w = (1.0f - z.w) * hv.w + z.w * g.w;
    *(float4*)&h[idx4] = hn;

    if (layer == 1) {
        ushort4 o;
        o.x = f2bf(hn.x); o.y = f2bf(hn.y); o.z = f2bf(hn.z); o.w = f2bf(hn.w);
        *(ushort4*)&h1bf[(size_t)t1 * (BATCH * HID) + idx4] = o;
    }
}

// ---------------------------------------------------------------------------
// Logits MFMA GEMM (R10 verbatim)
// ---------------------------------------------------------------------------
__global__ __launch_bounds__(256)
void logits_mfma_kernel(const ushort_t* __restrict__ Abf,
                        const ushort_t* __restrict__ BT,
                        const float* __restrict__ bout,
                        float* __restrict__ out)
{
    __shared__ ushort_t As[128 * 64];
    __shared__ ushort_t Bs[128 * 64];
    const int tid = threadIdx.x;
    const int wave = tid >> 6, lane = tid & 63;
    const int m0 = blockIdx.y * 128, n0 = blockIdx.x * 128;
    const int wr = wave >> 1, wc = wave & 1;

    const int srow = lane >> 3;
    const int sch = (lane & 7) ^ (srow & 7);
    const int lrow = lane & 15, lhi = lane >> 4;

    f32x4_t acc[4][4] = {};

    for (int k0 = 0; k0 < HID; k0 += 64) {
        #pragma unroll
        for (int i = 0; i < 4; ++i) {
            int issue = wave * 4 + i;
            int row = issue * 8 + srow;
            const ushort_t* ga = Abf + (size_t)(m0 + row) * HID + k0 + sch * 8;
            const ushort_t* gb = BT + (size_t)(n0 + row) * HID + k0 + sch * 8;
#ifdef HAVE_GLL
            __builtin_amdgcn_global_load_lds((gptr1_t)(const void*)ga,
                                             (lptr3_t)(void*)(As + issue * 512), 16, 0, 0);
            __builtin_amdgcn_global_load_lds((gptr1_t)(const void*)gb,
                                             (lptr3_t)(void*)(Bs + issue * 512), 16, 0, 0);
#else
            *(bf16x8_t*)(As + issue * 512 + lane * 8) = *(const bf16x8_t*)ga;
            *(bf16x8_t*)(Bs + issue * 512 + lane * 8) = *(const bf16x8_t*)gb;
#endif
        }
        __syncthreads();

        bf16x8_t af[4][2], bfm[4][2];
        const char* Ab = (const char*)As;
        const char* Bb = (const char*)Bs;
        #pragma unroll
        for (int m = 0; m < 4; ++m) {
            int row = wr * 64 + m * 16 + lrow;
            #pragma unroll
            for (int ks = 0; ks < 2; ++ks) {
                int off = row * 128 + (((ks * 4 + lhi) ^ (lrow & 7)) * 16);
                af[m][ks] = *(const bf16x8_t*)(Ab + off);
            }
        }
        #pragma unroll
        for (int n = 0; n < 4; ++n) {
            int row = wc * 64 + n * 16 + lrow;
            #pragma unroll
            for (int ks = 0; ks < 2; ++ks) {
                int off = row * 128 + (((ks * 4 + lhi) ^ (lrow & 7)) * 16);
                bfm[n][ks] = *(const bf16x8_t*)(Bb + off);
            }
        }
        #pragma unroll
        for (int m = 0; m < 4; ++m)
            #pragma unroll
            for (int n = 0; n < 4; ++n)
                #pragma unroll
                for (int ks = 0; ks < 2; ++ks)
                    acc[m][n] = __builtin_amdgcn_mfma_f32_16x16x32_bf16(
                        af[m][ks], bfm[n][ks], acc[m][n], 0, 0, 0);
        __syncthreads();
    }

    #pragma unroll
    for (int m = 0; m < 4; ++m) {
        int row = m0 + wr * 64 + m * 16 + lhi * 4;
        #pragma unroll
        for (int n = 0; n < 4; ++n) {
            int col = n0 + wc * 64 + n * 16 + lrow;
            if (col < VOCAB) {
                float bo = bout[col];
                #pragma unroll
                for (int q = 0; q < 4; ++q)
                    out[(size_t)(row + q) * VOCAB + col] = tanhf(acc[m][n][q] + bo);
            }
        }
    }
}

// ---------------------------------------------------------------------------
extern "C" void kernel_launch(void* const* d_in, const int* in_sizes, int n_in,
                              void* d_out, int out_size, void* d_ws, size_t ws_size,
                              hipStream_t stream)
{
    const int*   inputs = (const int*)  d_in[0];
    const float* hidden = (const float*)d_in[1];
    const float* emb    = (const float*)d_in[2];
    const float* Wr     = (const float*)d_in[3];
    const float* br     = (const float*)d_in[4];
    const float* Wz     = (const float*)d_in[5];
    const float* bz     = (const float*)d_in[6];
    const float* Wg     = (const float*)d_in[7];
    const float* bg     = (const float*)d_in[8];
    const float* Wout   = (const float*)d_in[9];
    const float* bout   = (const float*)d_in[10];
    float* out = (float*)d_out;

    const size_t BH = BATCH * HID;                 // 131072

    float* ws = (float*)d_ws;
    float* h0      = ws;                           // BH
    float* h1      = h0 + BH;                      // BH
    float* rh0     = h1 + BH;                      // BH
    float* rh1     = rh0 + BH;                     // BH
    float* part_rz = rh1 + BH;                     // 2*8*262144
    float* part_g  = part_rz + 2 * NSPLIT * (BATCH * 2 * HID);  // 2*8*131072
    float* xemb    = part_g + 2 * NSPLIT * (BATCH * HID);       // T*B*H
    ushort_t* h1bf = (ushort_t*)(xemb + (size_t)T_STEPS * BH);  // T*B*H bf16
    ushort_t* WT   = h1bf + (size_t)T_STEPS * BH;               // VPAD*H bf16

    init_h<<<(int)(BH + 255) / 256, 256, 0, stream>>>(hidden, h0, h1);
    gather_kernel<<<T_STEPS * BATCH, 256, 0, stream>>>(inputs, emb, xemb);
    woutT_kernel<<<dim3(VPAD / 32, HID / 32), 256, 0, stream>>>(Wout, WT);

    for (int s = 0; s <= T_STEPS; ++s) {
        int do0 = (s < T_STEPS) ? 1 : 0;
        int do1 = (s >= 1) ? 1 : 0;
        const float* xemb_t0 = xemb + (size_t)s * BH;
        agemm_k<<<dim3(32, NSPLIT, 2), 256, 0, stream>>>(
            xemb_t0, h0, h1, Wr, Wz, part_rz, do0, do1);
        aact_kernel<<<dim3(128, 2), 256, 0, stream>>>(
            part_rz, br, h0, h1, rh0, rh1, do0, do1);
        bgemm_k<<<dim3(32, NSPLIT, 2), 256, 0, stream>>>(
            xemb_t0, h0, h1, rh0, rh1, Wg, part_g, do0, do1);
        bact_kernel<<<dim3(128, 2), 256, 0, stream>>>(
            part_rz, part_g, bz, bg, h0, h1, h1bf, s - 1, do0, do1);
    }

    final_h<<<(int)(BH + 255) / 256, 256, 0, stream>>>(
        h0, h1, out + (size_t)T_STEPS * BATCH * VOCAB);

    logits_mfma_kernel<<<dim3(VPAD / 128, 8192 / 128), 256, 0, stream>>>(
        h1bf, WT, bout, out);
}